// Round 2
// baseline (816.031 us; speedup 1.0000x reference)
//
#include <hip/hip_runtime.h>

typedef unsigned short u16;
typedef unsigned int u32;
using bfrag = __attribute__((ext_vector_type(8))) short;   // 8 x bf16 (raw bits)
using facc  = __attribute__((ext_vector_type(4))) float;   // MFMA accumulator

// ---------------- numeric helpers ----------------
__device__ __forceinline__ u16 f2b(float f) {              // f32 -> bf16 (RNE)
  u32 u = __float_as_uint(f);
  return (u16)((u + 0x7FFFu + ((u >> 16) & 1u)) >> 16);
}
__device__ __forceinline__ float b2f(u16 h) { return __uint_as_float(((u32)h) << 16); }
// order-preserving float<->uint encoding for atomicMax-based scatter-max
__device__ __forceinline__ u32 encf(float f) {
  u32 u = __float_as_uint(f);
  return (u & 0x80000000u) ? ~u : (u | 0x80000000u);
}
__device__ __forceinline__ float decf(u32 e) {
  return __uint_as_float((e & 0x80000000u) ? (e & 0x7FFFFFFFu) : ~e);
}
__device__ __forceinline__ float mish_f(float v) {
  if (v > 15.f) return v;
  float ev = __expf(v);
  float p = ev * (ev + 2.f);
  return v * p / (p + 2.f);
}
__device__ __forceinline__ float ldf(const void* p, int i, int bf) {
  return bf ? b2f(((const u16*)p)[i]) : ((const float*)p)[i];
}
// Swizzled LDS tile: row stride 512B, XOR swizzle on bits 4..6
__device__ __forceinline__ u16* tptr(char* base, int row, int col) {
  int byt = ((row << 9) + (col << 1)) ^ ((row & 7) << 4);
  return (u16*)(base + byt);
}

// ---------------- dtype detector ----------------
__global__ void detect_dtype_kernel(const void* __restrict__ x, int* __restrict__ flag) {
  __shared__ int cnt;
  const int tid = threadIdx.x;
  if (tid == 0) cnt = 0;
  __syncthreads();
  const u16* p = (const u16*)x;
  u16 h = p[tid * 96 + 4];
  int e = (int)((h >> 7) & 0xFF);
  if (e >= 116 && e <= 134) atomicAdd(&cnt, 1);
  __syncthreads();
  if (tid == 0) *flag = (cnt >= 128) ? 1 : 0;
}

// ---------------- prep kernels ----------------
// Wt[n][k] = W[k][n] bf16, LDS-tiled transpose. grid 16, 256 thr.
__global__ void prep_transpose_kernel(const void* __restrict__ W, u16* __restrict__ Wt,
                                      const int* __restrict__ flag) {
  __shared__ u16 t[64][72];
  const int bf = *flag;
  const int bi = blockIdx.x >> 2, bj = blockIdx.x & 3;
  for (int it = 0; it < 16; ++it) {
    int l = threadIdx.x + (it << 8);
    int r = l >> 6, c = l & 63;
    t[r][c] = f2b(ldf(W, (bi * 64 + r) * 256 + bj * 64 + c, bf));
  }
  __syncthreads();
  for (int it = 0; it < 16; ++it) {
    int l = threadIdx.x + (it << 8);
    int r = l >> 6, c = l & 63;
    Wt[(bj * 64 + r) * 256 + bi * 64 + c] = t[c][r];
  }
}

// Wqkt[n][k] = sum_d Wq[k][d]*Wk[n][d], bf16. grid 256 (n), 256 thr (k). LDS-staged.
__global__ void prep_wqk_kernel(const void* __restrict__ Wq, const void* __restrict__ Wk,
                                u16* __restrict__ Wqkt, const int* __restrict__ flag) {
  __shared__ float wkrow[256];
  __shared__ u16 wqt[64][260];
  const int bf = *flag;
  const int n = blockIdx.x, k = threadIdx.x;
  wkrow[k] = ldf(Wk, (n << 8) + k, bf);
  float s = 0.f;
  for (int d0 = 0; d0 < 256; d0 += 64) {
    __syncthreads();
    for (int it = 0; it < 64; ++it) {
      int kk = (it << 2) + (threadIdx.x >> 6);
      int dd = threadIdx.x & 63;
      wqt[dd][kk] = f2b(ldf(Wq, (kk << 8) + d0 + dd, bf));
    }
    __syncthreads();
    #pragma unroll 8
    for (int dd = 0; dd < 64; ++dd) s += b2f(wqt[dd][k]) * wkrow[d0 + dd];
  }
  Wqkt[(n << 8) + k] = f2b(s);
}

// dqkp[q][d] = sum_n Wk[d][n]*dq[q][n] (rows 7..15 zero); uvec=Wq@bk; wvec=Wk@bq;
// dqc[q]=dq_q.bk, dqc[7]=bq.bk
__global__ void prep_vec_kernel(const void* __restrict__ Wq, const void* __restrict__ Wk,
                                const void* __restrict__ bq, const void* __restrict__ bk,
                                const void* __restrict__ dq,
                                u16* __restrict__ dqkp, float* __restrict__ uvec,
                                float* __restrict__ wvec, float* __restrict__ dqc,
                                const int* __restrict__ flag) {
  const int bf = *flag;
  const int blk = blockIdx.x, d = threadIdx.x;
  if (blk < 16) {
    float s = 0.f;
    if (blk < 7)
      for (int nn = 0; nn < 256; ++nn)
        s += ldf(Wk, (d << 8) + nn, bf) * ldf(dq, (blk << 8) + nn, bf);
    dqkp[(blk << 8) + d] = f2b(s);
  } else if (blk == 16) {
    float su = 0.f, sw = 0.f;
    for (int nn = 0; nn < 256; ++nn) {
      su += ldf(Wq, (d << 8) + nn, bf) * ldf(bk, nn, bf);
      sw += ldf(Wk, (d << 8) + nn, bf) * ldf(bq, nn, bf);
    }
    uvec[d] = su; wvec[d] = sw;
  } else {
    if (d < 7) {
      float s = 0.f;
      for (int nn = 0; nn < 256; ++nn) s += ldf(dq, (d << 8) + nn, bf) * ldf(bk, nn, bf);
      dqc[d] = s;
    } else if (d == 7) {
      float s = 0.f;
      for (int nn = 0; nn < 256; ++nn) s += ldf(bq, nn, bf) * ldf(bk, nn, bf);
      dqc[7] = s;
    }
  }
}

// rows 256..271 of Wqkt_ext: 256=uvec, 257=wvec, rest 0. grid 16, 256 thr.
__global__ void prep_ext_kernel(const float* __restrict__ uvec, const float* __restrict__ wvec,
                                u16* __restrict__ Wqkt_ext) {
  const int r = blockIdx.x, k = threadIdx.x;
  u16 v = 0;
  if (r == 0) v = f2b(uvec[k]);
  else if (r == 1) v = f2b(wvec[k]);
  Wqkt_ext[(256 + r) * 256 + k] = v;
}

// inverse tables: inv[from*81+to] -> policy slot (or -1)
__global__ void prep_inv_init_kernel(int* __restrict__ inv1, int* __restrict__ inv2) {
  int i = blockIdx.x * 256 + threadIdx.x;
  if (i < 6561) { inv1[i] = -1; inv2[i] = -1; }
}
__global__ void prep_inv_scatter_kernel(const int* __restrict__ valid_idx,
                                        const int* __restrict__ policy_idx,
                                        const int* __restrict__ promo_idx,
                                        const int* __restrict__ promo_policy_idx,
                                        int n_valid, int n_promo,
                                        int* __restrict__ inv1, int* __restrict__ inv2) {
  int i = blockIdx.x * 256 + threadIdx.x;
  if (i < n_valid) inv1[valid_idx[i]] = policy_idx[i];
  if (i < n_promo) inv2[promo_idx[i]] = promo_policy_idx[i];
}

// ---------------- K1: flattened pe + T + alpha/beta producer ----------------
// grid = M/64 blocks, 256 thr (4 waves). Wave w owns cols w*64..w*64+63, all 64 rows.
__device__ __forceinline__ bfrag load_x_frag(const void* x, long row, int col, int isbf) {
  if (isbf) {
    return *(const bfrag*)((const u16*)x + row * 256 + col);
  } else {
    const float* xf = (const float*)x + row * 256 + col;
    float4 v0 = *(const float4*)xf;
    float4 v1 = *(const float4*)(xf + 4);
    bfrag o;
    o[0] = (short)f2b(v0.x); o[1] = (short)f2b(v0.y); o[2] = (short)f2b(v0.z); o[3] = (short)f2b(v0.w);
    o[4] = (short)f2b(v1.x); o[5] = (short)f2b(v1.y); o[6] = (short)f2b(v1.z); o[7] = (short)f2b(v1.w);
    return o;
  }
}

__global__ __launch_bounds__(256, 4)
void k1_pe_T(const void* __restrict__ x, const void* __restrict__ b_embed,
             const u16* __restrict__ Wt_e, const u16* __restrict__ Wqkt_ext,
             const float* __restrict__ dqc,
             u16* __restrict__ pe_g, u16* __restrict__ T_g,
             float* __restrict__ alphaC, float* __restrict__ betaC,
             const int* __restrict__ dflag) {
  __shared__ char smem[32768];                 // pe tile [64][256] bf16, swizzled
  const int tid = threadIdx.x;
  const int lane = tid & 63;
  const int w = tid >> 6;
  const int lr = lane & 15;
  const int lg = lane >> 4;
  const int isbf = *dflag;
  const long row0 = (long)blockIdx.x * 64;

  // ---- stage 1: pe = mish(x @ We + b) ----
  {
    facc acc[4][4];
    facc z4 = {0.f, 0.f, 0.f, 0.f};
    #pragma unroll
    for (int i = 0; i < 4; ++i)
      #pragma unroll
      for (int j = 0; j < 4; ++j) acc[i][j] = z4;
    for (int k0 = 0; k0 < 256; k0 += 32) {
      bfrag a[4], bb[4];
      #pragma unroll
      for (int i = 0; i < 4; ++i)
        a[i] = load_x_frag(x, row0 + i * 16 + lr, k0 + (lg << 3), isbf);
      #pragma unroll
      for (int j = 0; j < 4; ++j)
        bb[j] = *(const bfrag*)(Wt_e + ((w * 64 + j * 16 + lr) << 8) + k0 + (lg << 3));
      #pragma unroll
      for (int i = 0; i < 4; ++i)
        #pragma unroll
        for (int j = 0; j < 4; ++j)
          acc[i][j] = __builtin_amdgcn_mfma_f32_16x16x32_bf16(a[i], bb[j], acc[i][j], 0, 0, 0);
    }
    #pragma unroll
    for (int j = 0; j < 4; ++j) {
      const int col = w * 64 + j * 16 + lr;
      const float bias = ldf(b_embed, col, isbf);
      #pragma unroll
      for (int i = 0; i < 4; ++i)
        #pragma unroll
        for (int r = 0; r < 4; ++r) {
          const int row = i * 16 + (lg << 2) + r;
          *tptr(smem, row, col) = f2b(mish_f(acc[i][j][r] + bias));
        }
    }
  }
  __syncthreads();

  // ---- copy pe LDS -> global (coalesced b128) ----
  for (int it = 0; it < 8; ++it) {
    int cidx = tid + (it << 8);
    int r = cidx >> 5, c8 = cidx & 31;
    bfrag v = *(const bfrag*)tptr(smem, r, c8 << 3);
    *(bfrag*)(pe_g + (row0 + r) * 256 + (c8 << 3)) = v;
  }

  // ---- stage 2: T = pe @ Wqk ----
  {
    facc acc[4][4];
    facc z4 = {0.f, 0.f, 0.f, 0.f};
    #pragma unroll
    for (int i = 0; i < 4; ++i)
      #pragma unroll
      for (int j = 0; j < 4; ++j) acc[i][j] = z4;
    for (int k0 = 0; k0 < 256; k0 += 32) {
      bfrag a[4], bb[4];
      #pragma unroll
      for (int i = 0; i < 4; ++i)
        a[i] = *(const bfrag*)tptr(smem, i * 16 + lr, k0 + (lg << 3));
      #pragma unroll
      for (int j = 0; j < 4; ++j)
        bb[j] = *(const bfrag*)(Wqkt_ext + ((w * 64 + j * 16 + lr) << 8) + k0 + (lg << 3));
      #pragma unroll
      for (int i = 0; i < 4; ++i)
        #pragma unroll
        for (int j = 0; j < 4; ++j)
          acc[i][j] = __builtin_amdgcn_mfma_f32_16x16x32_bf16(a[i], bb[j], acc[i][j], 0, 0, 0);
    }
    #pragma unroll
    for (int i = 0; i < 4; ++i)
      #pragma unroll
      for (int j = 0; j < 4; ++j) {
        const int col = w * 64 + j * 16 + lr;
        #pragma unroll
        for (int r = 0; r < 4; ++r) {
          const long row = row0 + i * 16 + (lg << 2) + r;
          T_g[row * 256 + col] = f2b(acc[i][j][r]);
        }
      }
  }

  // ---- mini-GEMM: alpha/beta for rows w*16..w*16+15 ----
  {
    facc ae = {0.f, 0.f, 0.f, 0.f};
    for (int k0 = 0; k0 < 256; k0 += 32) {
      bfrag a = *(const bfrag*)tptr(smem, w * 16 + lr, k0 + (lg << 3));
      bfrag bb = *(const bfrag*)(Wqkt_ext + ((256 + lr) << 8) + k0 + (lg << 3));
      ae = __builtin_amdgcn_mfma_f32_16x16x32_bf16(a, bb, ae, 0, 0, 0);
    }
    const float c = dqc[7];
    #pragma unroll
    for (int r = 0; r < 4; ++r) {
      const long row = row0 + w * 16 + (lg << 2) + r;
      if (lr == 0) alphaC[row] = (ae[r] + c) * 0.0625f;
      else if (lr == 1) betaC[row] = ae[r] * 0.0625f;
    }
  }
}

// ---------------- K2: per-batch board + scatter-max + drops ----------------
__global__ __launch_bounds__(256, 4)
void k2_board(const u16* __restrict__ pe_g, const u16* __restrict__ T_g,
              const u16* __restrict__ dqkp,
              const float* __restrict__ alphaC, const float* __restrict__ betaC,
              const float* __restrict__ dqc,
              const int* __restrict__ inv1, const int* __restrict__ inv2,
              void* __restrict__ out, const int* __restrict__ dflag) {
  __shared__ u32 pol[2187];
  const int tid = threadIdx.x;
  const int lane = tid & 63;
  const int w = tid >> 6;
  const int lr = lane & 15;
  const int lg = lane >> 4;
  const int b = blockIdx.x;
  const int isbf = *dflag;

  const u32 ENEG = encf(-1e10f);
  for (int i = tid; i < 2187; i += 256) pol[i] = ENEG;
  __syncthreads();

  const int wr = w >> 1, wc = w & 1;   // 2x2 wave grid over 96x96 board
  const u16* Tb = T_g + (size_t)b * 81 * 256;
  const u16* peb = pe_g + (size_t)b * 81 * 256;

  facc acc[3][3];
  {
    facc z4 = {0.f, 0.f, 0.f, 0.f};
    #pragma unroll
    for (int i = 0; i < 3; ++i)
      #pragma unroll
      for (int j = 0; j < 3; ++j) acc[i][j] = z4;
  }
  for (int k0 = 0; k0 < 256; k0 += 32) {
    bfrag a[3], bb[3];
    #pragma unroll
    for (int i = 0; i < 3; ++i) {
      int r = wr * 48 + i * 16 + lr;
      const u16* ap = (r < 81) ? (Tb + (size_t)r * 256) : (dqkp + (size_t)(r - 81) * 256);
      a[i] = *(const bfrag*)(ap + k0 + (lg << 3));
    }
    #pragma unroll
    for (int j = 0; j < 3; ++j) {
      int t = wc * 48 + j * 16 + lr;
      bb[j] = *(const bfrag*)(peb + (size_t)t * 256 + k0 + (lg << 3));
    }
    #pragma unroll
    for (int i = 0; i < 3; ++i)
      #pragma unroll
      for (int j = 0; j < 3; ++j)
        acc[i][j] = __builtin_amdgcn_mfma_f32_16x16x32_bf16(a[i], bb[j], acc[i][j], 0, 0, 0);
  }

  // epilogue: alpha/beta add + inverse-table scatter-max + drop rows
  #pragma unroll
  for (int j = 0; j < 3; ++j) {
    const int colb = wc * 48 + j * 16 + lr;
    const float bet = (colb < 81) ? betaC[b * 81 + colb] : 0.f;
    #pragma unroll
    for (int i = 0; i < 3; ++i) {
      #pragma unroll
      for (int r = 0; r < 4; ++r) {
        const int rowb = wr * 48 + i * 16 + (lg << 2) + r;
        const float v = acc[i][j][r] * 0.0625f;
        if (rowb < 81 && colb < 81) {
          const float vv = v + alphaC[b * 81 + rowb] + bet;
          const int m = rowb * 81 + colb;
          const int i1 = inv1[m];
          if (i1 >= 0) atomicMax(&pol[i1], encf(vv));
          const int i2 = inv2[m];
          if (i2 >= 0) atomicMax(&pol[i2], encf(vv));
        } else if (rowb >= 81 && rowb < 88 && colb < 81) {
          pol[1620 + (rowb - 81) * 81 + colb] = encf(v + dqc[rowb - 81] * 0.0625f);
        }
      }
    }
  }
  __syncthreads();

  if (isbf) {
    u16* ob = (u16*)out + (size_t)b * 2187u;
    for (int p2 = tid; p2 < 2187; p2 += 256) ob[p2] = f2b(decf(pol[p2]));
  } else {
    float* ob = (float*)out + (size_t)b * 2187u;
    for (int p2 = tid; p2 < 2187; p2 += 256) ob[p2] = decf(pol[p2]);
  }
}

// ================= round-1 fused kernel kept as ws-size fallback =================
#define LDS_TOTAL 146240
__global__ __launch_bounds__(512)
void dirpolicy_fused(const void* __restrict__ x,
                     const void* __restrict__ b_embed,
                     const u16* __restrict__ Wt_e,
                     const u16* __restrict__ Wqkt,
                     const u16* __restrict__ dqkp,
                     const float* __restrict__ uvec,
                     const float* __restrict__ wvec,
                     const float* __restrict__ dqc,
                     const int* __restrict__ valid_idx,
                     const int* __restrict__ policy_idx,
                     const int* __restrict__ promo_idx,
                     const int* __restrict__ promo_policy_idx,
                     int n_valid, int n_promo,
                     void* __restrict__ out,
                     const int* __restrict__ dflag) {
  extern __shared__ char smem[];
  char* bufA = smem;
  char* bufB = smem + 49152;
  float* board = (float*)(smem + 98304);
  u32* pol = (u32*)(smem + 136704);
  float* alpha = (float*)(smem + 145472);
  float* beta  = (float*)(smem + 145856);
  const int tid = threadIdx.x;
  const int lane = tid & 63;
  const int w = tid >> 6;
  const int lr = lane & 15;
  const int lg = lane >> 4;
  const int isbf = *dflag;
  if (isbf) {
    const u16* xb = (const u16*)x + (size_t)blockIdx.x * 20736u;
    for (int i = tid; i < 2592; i += 512) {
      bfrag v = *(const bfrag*)(xb + (i << 3));
      *(bfrag*)tptr(bufA, i >> 5, (i & 31) << 3) = v;
    }
  } else {
    const float4* xs = (const float4*)((const float*)x + (size_t)blockIdx.x * 20736u);
    for (int i = tid; i < 5184; i += 512) {
      float4 v = xs[i];
      ushort4 h;
      h.x = f2b(v.x); h.y = f2b(v.y); h.z = f2b(v.z); h.w = f2b(v.w);
      *(ushort4*)tptr(bufA, i >> 6, (i & 63) << 2) = h;
    }
  }
  {
    bfrag z = {0, 0, 0, 0, 0, 0, 0, 0};
    for (int i = tid; i < 480; i += 512)
      *(bfrag*)tptr(bufA, 81 + (i >> 5), (i & 31) << 3) = z;
  }
  __syncthreads();
  const int rg = w >> 2;
  const int cg = w & 3;
  {
    facc acc[3][4];
    facc z4 = {0.f, 0.f, 0.f, 0.f};
    for (int i = 0; i < 3; ++i) for (int j = 0; j < 4; ++j) acc[i][j] = z4;
    for (int k0 = 0; k0 < 256; k0 += 32) {
      bfrag a[3], bb[4];
      for (int i = 0; i < 3; ++i)
        a[i] = *(const bfrag*)tptr(bufA, rg * 48 + i * 16 + lr, k0 + (lg << 3));
      for (int j = 0; j < 4; ++j)
        bb[j] = *(const bfrag*)(Wt_e + ((cg * 64 + j * 16 + lr) << 8) + k0 + (lg << 3));
      for (int i = 0; i < 3; ++i)
        for (int j = 0; j < 4; ++j)
          acc[i][j] = __builtin_amdgcn_mfma_f32_16x16x32_bf16(a[i], bb[j], acc[i][j], 0, 0, 0);
    }
    for (int i = 0; i < 3; ++i)
      for (int j = 0; j < 4; ++j) {
        const int col = cg * 64 + j * 16 + lr;
        const float bias = ldf(b_embed, col, isbf);
        for (int r = 0; r < 4; ++r) {
          const int row = rg * 48 + i * 16 + (lg << 2) + r;
          *tptr(bufB, row, col) = f2b(mish_f(acc[i][j][r] + bias));
        }
      }
  }
  __syncthreads();
  {
    facc acc[3][4];
    facc z4 = {0.f, 0.f, 0.f, 0.f};
    for (int i = 0; i < 3; ++i) for (int j = 0; j < 4; ++j) acc[i][j] = z4;
    for (int k0 = 0; k0 < 256; k0 += 32) {
      bfrag a[3], bb[4];
      for (int i = 0; i < 3; ++i)
        a[i] = *(const bfrag*)tptr(bufB, rg * 48 + i * 16 + lr, k0 + (lg << 3));
      for (int j = 0; j < 4; ++j)
        bb[j] = *(const bfrag*)(Wqkt + ((cg * 64 + j * 16 + lr) << 8) + k0 + (lg << 3));
      for (int i = 0; i < 3; ++i)
        for (int j = 0; j < 4; ++j)
          acc[i][j] = __builtin_amdgcn_mfma_f32_16x16x32_bf16(a[i], bb[j], acc[i][j], 0, 0, 0);
    }
    for (int i = 0; i < 3; ++i)
      for (int j = 0; j < 4; ++j) {
        const int col = cg * 64 + j * 16 + lr;
        for (int r = 0; r < 4; ++r) {
          const int row = rg * 48 + i * 16 + (lg << 2) + r;
          *tptr(bufA, row, col) = f2b(acc[i][j][r]);
        }
      }
  }
  __syncthreads();
  facc accu[6];
  {
    facc z4 = {0.f, 0.f, 0.f, 0.f};
    for (int i = 0; i < 6; ++i) accu[i] = z4;
  }
  int rg3 = 0, cg3 = 0;
  if (w < 6) {
    rg3 = (w >= 3) ? 1 : 0;
    cg3 = w - rg3 * 3;
    for (int k0 = 0; k0 < 256; k0 += 32) {
      bfrag a[3], bb[2];
      for (int i = 0; i < 3; ++i)
        a[i] = *(const bfrag*)tptr(bufA, rg3 * 48 + i * 16 + lr, k0 + (lg << 3));
      for (int j = 0; j < 2; ++j)
        bb[j] = *(const bfrag*)tptr(bufB, (cg3 * 2 + j) * 16 + lr, k0 + (lg << 3));
      for (int i = 0; i < 3; ++i)
        for (int j = 0; j < 2; ++j)
          accu[i * 2 + j] = __builtin_amdgcn_mfma_f32_16x16x32_bf16(a[i], bb[j], accu[i * 2 + j], 0, 0, 0);
    }
  } else if (w == 6) {
    for (int k0 = 0; k0 < 256; k0 += 32) {
      bfrag a = *(const bfrag*)(dqkp + (lr << 8) + k0 + (lg << 3));
      for (int t = 0; t < 6; ++t) {
        bfrag bb = *(const bfrag*)tptr(bufB, t * 16 + lr, k0 + (lg << 3));
        accu[t] = __builtin_amdgcn_mfma_f32_16x16x32_bf16(a, bb, accu[t], 0, 0, 0);
      }
    }
  } else {
    const u32 ENEG = encf(-1e10f);
    for (int i = lane; i < 2187; i += 64) pol[i] = ENEG;
    for (int row = lane; row < 96; row += 64) {
      float sa = 0.f, sb = 0.f;
      for (int k = 0; k < 256; k += 4) {
        ushort4 pv = *(const ushort4*)tptr(bufB, row, k);
        float p0 = b2f(pv.x), p1 = b2f(pv.y), p2 = b2f(pv.z), p3 = b2f(pv.w);
        sa += p0 * uvec[k] + p1 * uvec[k + 1] + p2 * uvec[k + 2] + p3 * uvec[k + 3];
        sb += p0 * wvec[k] + p1 * wvec[k + 1] + p2 * wvec[k + 2] + p3 * wvec[k + 3];
      }
      alpha[row] = sa;
      beta[row] = sb;
    }
  }
  __syncthreads();
  if (w < 6) {
    const float c = dqc[7];
    for (int i = 0; i < 3; ++i)
      for (int j = 0; j < 2; ++j) {
        const int col = (cg3 * 2 + j) * 16 + lr;
        for (int r = 0; r < 4; ++r) {
          const int row = rg3 * 48 + i * 16 + (lg << 2) + r;
          board[row * 100 + col] = (accu[i * 2 + j][r] + alpha[row] + beta[col] + c) * 0.0625f;
        }
      }
  } else if (w == 6) {
    for (int t = 0; t < 6; ++t)
      for (int r = 0; r < 4; ++r) {
        const int q = (lg << 2) + r;
        const int tc = t * 16 + lr;
        if (q < 7 && tc < 81)
          pol[1620 + q * 81 + tc] = encf((accu[t][r] + dqc[q]) * 0.0625f);
      }
  }
  __syncthreads();
  for (int i = tid; i < n_valid; i += 512) {
    int src = valid_idx[i];
    int s = src / 81;
    int t = src - s * 81;
    atomicMax(&pol[policy_idx[i]], encf(board[s * 100 + t]));
  }
  for (int i = tid; i < n_promo; i += 512) {
    int src = promo_idx[i];
    int s = src / 81;
    int t = src - s * 81;
    atomicMax(&pol[promo_policy_idx[i]], encf(board[s * 100 + t]));
  }
  __syncthreads();
  if (isbf) {
    u16* ob = (u16*)out + (size_t)blockIdx.x * 2187u;
    for (int p2 = tid; p2 < 2187; p2 += 512) ob[p2] = f2b(decf(pol[p2]));
  } else {
    float* ob = (float*)out + (size_t)blockIdx.x * 2187u;
    for (int p2 = tid; p2 < 2187; p2 += 512) ob[p2] = decf(pol[p2]);
  }
}

// ---------------- launcher ----------------
extern "C" void kernel_launch(void* const* d_in, const int* in_sizes, int n_in,
                              void* d_out, int out_size, void* d_ws, size_t ws_size,
                              hipStream_t stream) {
  const void* x        = d_in[0];
  const void* W_embed  = d_in[1];
  const void* b_embed  = d_in[2];
  const void* Wq       = d_in[3];
  const void* bq       = d_in[4];
  const void* bk_      = d_in[6];
  const void* Wk       = d_in[5];
  const void* dq       = d_in[7];
  const int* valid_idx         = (const int*)d_in[8];
  const int* policy_idx        = (const int*)d_in[9];
  const int* promo_idx         = (const int*)d_in[10];
  const int* promo_policy_idx  = (const int*)d_in[11];
  const int n_valid = in_sizes[8];
  const int n_promo = in_sizes[10];
  const int B = in_sizes[0] / 20736;   // 81*256
  const long M = (long)B * 81;

  // ws layout
  char* ws = (char*)d_ws;
  u16* Wt_e     = (u16*)(ws);                    // 131072
  u16* Wqkt_ext = (u16*)(ws + 131072);           // 272*256*2 = 139264
  u16* dqkp     = (u16*)(ws + 270336);           // 8192
  float* uvec   = (float*)(ws + 278528);         // 1024
  float* wvec   = (float*)(ws + 279552);         // 1024
  float* dqc    = (float*)(ws + 280576);         // 64
  int* dflag    = (int*)(ws + 280640);           // 64
  int* inv1     = (int*)(ws + 280704);           // 26368 (pad)
  int* inv2     = (int*)(ws + 307072);           // 26368
  float* alphaC = (float*)(ws + 333440);         // M*4 = 1327104
  float* betaC  = (float*)(ws + 1660544);        // 1327104
  u16* pe_g     = (u16*)(ws + 2987776);          // (M+16)*256*2
  u16* T_g      = (u16*)(ws + 172865280);        // (M+16)*256*2
  const size_t NEED = 342742784ULL;

  if (ws_size < 333440) return;   // can't even run fallback

  detect_dtype_kernel<<<dim3(1), dim3(256), 0, stream>>>(x, dflag);
  prep_transpose_kernel<<<dim3(16), dim3(256), 0, stream>>>(W_embed, Wt_e, dflag);
  prep_wqk_kernel<<<dim3(256), dim3(256), 0, stream>>>(Wq, Wk, Wqkt_ext, dflag);
  prep_vec_kernel<<<dim3(18), dim3(256), 0, stream>>>(Wq, Wk, bq, bk_, dq,
                                                      dqkp, uvec, wvec, dqc, dflag);

  if (ws_size >= NEED && (M % 64) == 0) {
    prep_ext_kernel<<<dim3(16), dim3(256), 0, stream>>>(uvec, wvec, Wqkt_ext);
    prep_inv_init_kernel<<<dim3(26), dim3(256), 0, stream>>>(inv1, inv2);
    int mx = n_valid > n_promo ? n_valid : n_promo;
    prep_inv_scatter_kernel<<<dim3((mx + 255) / 256), dim3(256), 0, stream>>>(
        valid_idx, policy_idx, promo_idx, promo_policy_idx, n_valid, n_promo, inv1, inv2);

    k1_pe_T<<<dim3((int)(M / 64)), dim3(256), 0, stream>>>(
        x, b_embed, Wt_e, Wqkt_ext, dqc, pe_g, T_g, alphaC, betaC, dflag);
    k2_board<<<dim3(B), dim3(256), 0, stream>>>(
        pe_g, T_g, dqkp, alphaC, betaC, dqc, inv1, inv2, d_out, dflag);
  } else {
    (void)hipFuncSetAttribute((const void*)dirpolicy_fused,
                              hipFuncAttributeMaxDynamicSharedMemorySize, LDS_TOTAL);
    dirpolicy_fused<<<dim3(B), dim3(512), LDS_TOTAL, stream>>>(
        x, b_embed, Wt_e, Wqkt_ext, dqkp, uvec, wvec, dqc,
        valid_idx, policy_idx, promo_idx, promo_policy_idx,
        n_valid, n_promo, d_out, dflag);
  }
}

// Round 3
// 532.204 us; speedup vs baseline: 1.5333x; 1.5333x over previous
//
#include <hip/hip_runtime.h>

typedef unsigned short u16;
typedef unsigned int u32;
using bfrag = __attribute__((ext_vector_type(8))) short;   // 8 x bf16 (raw bits)
using facc  = __attribute__((ext_vector_type(4))) float;   // MFMA accumulator

// ---------------- numeric helpers ----------------
__device__ __forceinline__ u16 f2b(float f) {              // f32 -> bf16 (RNE)
  u32 u = __float_as_uint(f);
  return (u16)((u + 0x7FFFu + ((u >> 16) & 1u)) >> 16);
}
__device__ __forceinline__ float b2f(u16 h) { return __uint_as_float(((u32)h) << 16); }
__device__ __forceinline__ u32 encf(float f) {             // order-preserving f32->u32
  u32 u = __float_as_uint(f);
  return (u & 0x80000000u) ? ~u : (u | 0x80000000u);
}
__device__ __forceinline__ float decf(u32 e) {
  return __uint_as_float((e & 0x80000000u) ? (e & 0x7FFFFFFFu) : ~e);
}
__device__ __forceinline__ float mish_f(float v) {
  if (v > 15.f) return v;
  float ev = __expf(v);
  float p = ev * (ev + 2.f);
  return v * p / (p + 2.f);
}
__device__ __forceinline__ float ldf(const void* p, int i, int bf) {
  return bf ? b2f(((const u16*)p)[i]) : ((const float*)p)[i];
}
// Swizzled LDS tile [96][256] bf16: row stride 512B, XOR swizzle bits 4..6.
// Fragment reads (16 lanes, same col, rows r0..r0+15) land 2 lanes/bank = free.
__device__ __forceinline__ u16* tptr(char* base, int row, int col) {
  int byt = ((row << 9) + (col << 1)) ^ ((row & 7) << 4);
  return (u16*)(base + byt);
}

// ---------------- dtype detector ----------------
__global__ void detect_dtype_kernel(const void* __restrict__ x, int* __restrict__ flag) {
  __shared__ int cnt;
  const int tid = threadIdx.x;
  if (tid == 0) cnt = 0;
  __syncthreads();
  const u16* p = (const u16*)x;
  u16 h = p[tid * 96 + 4];
  int e = (int)((h >> 7) & 0xFF);
  if (e >= 116 && e <= 134) atomicAdd(&cnt, 1);
  __syncthreads();
  if (tid == 0) *flag = (cnt >= 128) ? 1 : 0;
}

// ---------------- prep kernels ----------------
// Wt[n][k] = W[k][n] bf16 (LDS-tiled transpose). grid 16, 256 thr.
__global__ void prep_transpose_kernel(const void* __restrict__ W, u16* __restrict__ Wt,
                                      const int* __restrict__ flag) {
  __shared__ u16 t[64][72];
  const int bf = *flag;
  const int bi = blockIdx.x >> 2, bj = blockIdx.x & 3;
  for (int it = 0; it < 16; ++it) {
    int l = threadIdx.x + (it << 8);
    int r = l >> 6, c = l & 63;
    t[r][c] = f2b(ldf(W, (bi * 64 + r) * 256 + bj * 64 + c, bf));
  }
  __syncthreads();
  for (int it = 0; it < 16; ++it) {
    int l = threadIdx.x + (it << 8);
    int r = l >> 6, c = l & 63;
    Wt[(bj * 64 + r) * 256 + bi * 64 + c] = t[c][r];
  }
}

// Wqkt[n][k] = sum_d Wq[k][d]*Wk[n][d], bf16. grid 256 (n), 256 thr (k).
__global__ void prep_wqk_kernel(const void* __restrict__ Wq, const void* __restrict__ Wk,
                                u16* __restrict__ Wqkt, const int* __restrict__ flag) {
  __shared__ float wkrow[256];
  __shared__ u16 wqt[64][260];
  const int bf = *flag;
  const int n = blockIdx.x, k = threadIdx.x;
  wkrow[k] = ldf(Wk, (n << 8) + k, bf);
  float s = 0.f;
  for (int d0 = 0; d0 < 256; d0 += 64) {
    __syncthreads();
    for (int it = 0; it < 64; ++it) {
      int kk = (it << 2) + (threadIdx.x >> 6);
      int dd = threadIdx.x & 63;
      wqt[dd][kk] = f2b(ldf(Wq, (kk << 8) + d0 + dd, bf));
    }
    __syncthreads();
    #pragma unroll 8
    for (int dd = 0; dd < 64; ++dd) s += b2f(wqt[dd][k]) * wkrow[d0 + dd];
  }
  Wqkt[(n << 8) + k] = f2b(s);
}

// dqkp[q][d] = sum_n Wk[d][n]*dq[q][n]; uvec=Wq@bk; wvec=Wk@bq; dqc[q]=dq_q.bk, dqc[7]=bq.bk
__global__ void prep_vec_kernel(const void* __restrict__ Wq, const void* __restrict__ Wk,
                                const void* __restrict__ bq, const void* __restrict__ bk,
                                const void* __restrict__ dq,
                                u16* __restrict__ dqkp, float* __restrict__ uvec,
                                float* __restrict__ wvec, float* __restrict__ dqc,
                                const int* __restrict__ flag) {
  const int bf = *flag;
  const int blk = blockIdx.x, d = threadIdx.x;
  if (blk < 16) {
    float s = 0.f;
    if (blk < 7)
      for (int nn = 0; nn < 256; ++nn)
        s += ldf(Wk, (d << 8) + nn, bf) * ldf(dq, (blk << 8) + nn, bf);
    dqkp[(blk << 8) + d] = f2b(s);
  } else if (blk == 16) {
    float su = 0.f, sw = 0.f;
    for (int nn = 0; nn < 256; ++nn) {
      su += ldf(Wq, (d << 8) + nn, bf) * ldf(bk, nn, bf);
      sw += ldf(Wk, (d << 8) + nn, bf) * ldf(bq, nn, bf);
    }
    uvec[d] = su; wvec[d] = sw;
  } else {
    if (d < 7) {
      float s = 0.f;
      for (int nn = 0; nn < 256; ++nn) s += ldf(dq, (d << 8) + nn, bf) * ldf(bk, nn, bf);
      dqc[d] = s;
    } else if (d == 7) {
      float s = 0.f;
      for (int nn = 0; nn < 256; ++nn) s += ldf(bq, nn, bf) * ldf(bk, nn, bf);
      dqc[7] = s;
    }
  }
}

// Pack a [n][k] bf16 256x256 matrix into MFMA-fragment tiles:
// dst[tile*512 + lane*8 + e], tile = nt*8 + kt, lane = lg*16+lr, covers
// B[n = nt*16+lr][k = kt*32 + lg*8 + e]. One wave-load = 1KB contiguous.
__global__ void prep_pack_tiled(const u16* __restrict__ src, u16* __restrict__ dst) {
  int t = blockIdx.x * 256 + threadIdx.x;      // 8192 threads
  int l = t & 63, tile = t >> 6;
  int kt = tile & 7, nt = tile >> 3;
  int lr = l & 15, lg = l >> 4;
  int n = nt * 16 + lr, k = kt * 32 + lg * 8;
  bfrag v = *(const bfrag*)(src + (n << 8) + k);
  *(bfrag*)(dst + (t << 3)) = v;
}

// uvw tiled: n-rows = [uvec; wvec; 0...], 8 k-tiles. 512 threads.
__global__ void prep_uvw_tiled(const float* __restrict__ uvec, const float* __restrict__ wvec,
                               u16* __restrict__ dst) {
  int t = blockIdx.x * 256 + threadIdx.x;      // 512 threads
  int l = t & 63, kt = t >> 6;
  int lr = l & 15, lg = l >> 4;
  int k = kt * 32 + lg * 8;
  bfrag o;
  #pragma unroll
  for (int e = 0; e < 8; ++e) {
    float v = (lr == 0) ? uvec[k + e] : (lr == 1) ? wvec[k + e] : 0.f;
    o[e] = (short)f2b(v);
  }
  *(bfrag*)(dst + (t << 3)) = o;
}

// inverse tables packed: inv12[m] = (slot1, slot2) or -1
__global__ void prep_inv_init_kernel(int2* __restrict__ inv12) {
  int i = blockIdx.x * 256 + threadIdx.x;
  if (i < 6561) inv12[i] = make_int2(-1, -1);
}
__global__ void prep_inv_scatter_kernel(const int* __restrict__ valid_idx,
                                        const int* __restrict__ policy_idx,
                                        const int* __restrict__ promo_idx,
                                        const int* __restrict__ promo_policy_idx,
                                        int n_valid, int n_promo,
                                        int2* __restrict__ inv12) {
  int i = blockIdx.x * 256 + threadIdx.x;
  if (i < n_valid) inv12[valid_idx[i]].x = policy_idx[i];
  if (i < n_promo) inv12[promo_idx[i]].y = promo_policy_idx[i];
}

// ---------------- fused one-pass kernel: one block per batch element ----------------
// LDS: bufA [96][256] bf16 swz (x -> pe)  @      0 (49152)
//      bufT [96][256] bf16 swz ([T;dqkp]) @  49152 (49152)
//      pol  [2187] u32                    @  98304 ( 8768)
//      alpha[96] f32, beta[96] f32        @ 107072 / 107456
#define LDS_TOTAL 107840

__global__ __launch_bounds__(512, 2)
void dirpolicy_onepass(const void* __restrict__ x,
                       const void* __restrict__ b_embed,
                       const u16* __restrict__ Wt_tl,
                       const u16* __restrict__ Wqkt_tl,
                       const u16* __restrict__ uvwt,
                       const u16* __restrict__ dqkp,
                       const float* __restrict__ dqc,
                       const int2* __restrict__ inv12,
                       void* __restrict__ out,
                       const int* __restrict__ dflag) {
  extern __shared__ char smem[];
  char* bufA = smem;
  char* bufT = smem + 49152;
  u32* pol = (u32*)(smem + 98304);
  float* alpha = (float*)(smem + 107072);
  float* beta  = (float*)(smem + 107456);

  const int tid = threadIdx.x;
  const int lane = tid & 63;
  const int w = tid >> 6;        // wave 0..7
  const int lr = lane & 15;
  const int lg = lane >> 4;
  const int isbf = *dflag;
  const int b = blockIdx.x;
  const u32 ENEG = encf(-1e10f);

  // ================= phase 0: stage x + init =================
  if (isbf) {
    const u16* xb = (const u16*)x + (size_t)b * 20736u;
    bfrag xr[6];
    #pragma unroll
    for (int c = 0; c < 6; ++c) {                      // issue all loads first
      int i = tid + (c << 9);
      if (i < 2592) xr[c] = *(const bfrag*)(xb + (i << 3));
    }
    // overlap: pol init + dqkp rows + zero pads while x is in flight
    for (int i = tid; i < 2187; i += 512) pol[i] = ENEG;
    for (int i = tid; i < 1792; i += 512) {
      int q = i >> 8, k = i & 255;
      *tptr(bufT, 81 + q, k) = dqkp[(q << 8) + k];
    }
    for (int i = tid; i < 2048; i += 512) *tptr(bufT, 88 + (i >> 8), i & 255) = 0;
    {
      bfrag z = {0,0,0,0,0,0,0,0};
      for (int i = tid; i < 480; i += 512)
        *(bfrag*)tptr(bufA, 81 + (i >> 5), (i & 31) << 3) = z;
    }
    #pragma unroll
    for (int c = 0; c < 6; ++c) {
      int i = tid + (c << 9);
      if (i < 2592) *(bfrag*)tptr(bufA, i >> 5, (i & 31) << 3) = xr[c];
    }
  } else {
    const float4* xs = (const float4*)((const float*)x + (size_t)b * 20736u);
    float4 xr[11];
    #pragma unroll
    for (int c = 0; c < 11; ++c) {
      int i = tid + (c << 9);
      if (i < 5184) xr[c] = xs[i];
    }
    for (int i = tid; i < 2187; i += 512) pol[i] = ENEG;
    for (int i = tid; i < 1792; i += 512) {
      int q = i >> 8, k = i & 255;
      *tptr(bufT, 81 + q, k) = dqkp[(q << 8) + k];
    }
    for (int i = tid; i < 2048; i += 512) *tptr(bufT, 88 + (i >> 8), i & 255) = 0;
    {
      bfrag z = {0,0,0,0,0,0,0,0};
      for (int i = tid; i < 480; i += 512)
        *(bfrag*)tptr(bufA, 81 + (i >> 5), (i & 31) << 3) = z;
    }
    #pragma unroll
    for (int c = 0; c < 11; ++c) {
      int i = tid + (c << 9);
      if (i < 5184) {
        ushort4 h;
        h.x = f2b(xr[c].x); h.y = f2b(xr[c].y); h.z = f2b(xr[c].z); h.w = f2b(xr[c].w);
        *(ushort4*)tptr(bufA, i >> 6, (i & 63) << 2) = h;
      }
    }
  }
  __syncthreads();

  const int wr = w >> 2;   // 0..1 : rows wr*48..+47
  const int wc = w & 3;    // 0..3 : cols wc*64..+63

  // ================= phase 1: pe = mish(x @ We + b) =================
  facc acc[3][4];
  {
    facc z4 = {0.f, 0.f, 0.f, 0.f};
    #pragma unroll
    for (int i = 0; i < 3; ++i)
      #pragma unroll
      for (int j = 0; j < 4; ++j) acc[i][j] = z4;
    // preload ALL B fragments for this wave's 64 output cols (32 x 16B, coalesced 1KB/wave)
    bfrag B1[8][4];
    #pragma unroll
    for (int kt = 0; kt < 8; ++kt)
      #pragma unroll
      for (int j = 0; j < 4; ++j)
        B1[kt][j] = *(const bfrag*)(Wt_tl + (((((wc << 2) + j) << 3) + kt) << 9) + (lane << 3));
    #pragma unroll
    for (int kt = 0; kt < 8; ++kt) {
      bfrag a[3];
      #pragma unroll
      for (int i = 0; i < 3; ++i)
        a[i] = *(const bfrag*)tptr(bufA, wr * 48 + i * 16 + lr, (kt << 5) + (lg << 3));
      #pragma unroll
      for (int i = 0; i < 3; ++i)
        #pragma unroll
        for (int j = 0; j < 4; ++j)
          acc[i][j] = __builtin_amdgcn_mfma_f32_16x16x32_bf16(a[i], B1[kt][j], acc[i][j], 0, 0, 0);
    }
  }
  __syncthreads();                       // all waves done reading x
  // epilogue: pe overwrites bufA
  #pragma unroll
  for (int j = 0; j < 4; ++j) {
    const int col = (wc << 6) + j * 16 + lr;
    const float bias = ldf(b_embed, col, isbf);
    #pragma unroll
    for (int i = 0; i < 3; ++i)
      #pragma unroll
      for (int r = 0; r < 4; ++r) {
        const int row = wr * 48 + i * 16 + (lg << 2) + r;
        *tptr(bufA, row, col) = f2b(mish_f(acc[i][j][r] + bias));
      }
  }
  // preload phase-3 B fragments while pe settles (overlaps with barrier + mini)
  bfrag B2[8][4];
  #pragma unroll
  for (int kt = 0; kt < 8; ++kt)
    #pragma unroll
    for (int j = 0; j < 4; ++j)
      B2[kt][j] = *(const bfrag*)(Wqkt_tl + (((((wc << 2) + j) << 3) + kt) << 9) + (lane << 3));
  __syncthreads();                       // pe visible

  // ================= phase 2: alpha/beta mini-GEMM (waves 0..5) =================
  if (w < 6) {
    bfrag U[8];
    #pragma unroll
    for (int kt = 0; kt < 8; ++kt)
      U[kt] = *(const bfrag*)(uvwt + (kt << 9) + (lane << 3));
    facc ae = {0.f, 0.f, 0.f, 0.f};
    #pragma unroll
    for (int kt = 0; kt < 8; ++kt) {
      bfrag a = *(const bfrag*)tptr(bufA, w * 16 + lr, (kt << 5) + (lg << 3));
      ae = __builtin_amdgcn_mfma_f32_16x16x32_bf16(a, U[kt], ae, 0, 0, 0);
    }
    const float c = dqc[7];
    #pragma unroll
    for (int r = 0; r < 4; ++r) {
      const int row = w * 16 + (lg << 2) + r;
      if (lr == 0) alpha[row] = (ae[r] + c) * 0.0625f;
      else if (lr == 1) beta[row] = ae[r] * 0.0625f;
    }
  }

  // ================= phase 3: T = pe @ Wqk -> bufT rows 0..80 =================
  {
    facc acc2[3][4];
    facc z4 = {0.f, 0.f, 0.f, 0.f};
    #pragma unroll
    for (int i = 0; i < 3; ++i)
      #pragma unroll
      for (int j = 0; j < 4; ++j) acc2[i][j] = z4;
    #pragma unroll
    for (int kt = 0; kt < 8; ++kt) {
      bfrag a[3];
      #pragma unroll
      for (int i = 0; i < 3; ++i)
        a[i] = *(const bfrag*)tptr(bufA, wr * 48 + i * 16 + lr, (kt << 5) + (lg << 3));
      #pragma unroll
      for (int i = 0; i < 3; ++i)
        #pragma unroll
        for (int j = 0; j < 4; ++j)
          acc2[i][j] = __builtin_amdgcn_mfma_f32_16x16x32_bf16(a[i], B2[kt][j], acc2[i][j], 0, 0, 0);
    }
    #pragma unroll
    for (int i = 0; i < 3; ++i)
      #pragma unroll
      for (int j = 0; j < 4; ++j) {
        const int col = (wc << 6) + j * 16 + lr;
        #pragma unroll
        for (int r = 0; r < 4; ++r) {
          const int row = wr * 48 + i * 16 + (lg << 2) + r;
          if (row < 81) *tptr(bufT, row, col) = f2b(acc2[i][j][r]);
        }
      }
  }
  __syncthreads();                       // T + alpha/beta ready

  // ================= phase 4: board = [T;dqkp] @ pe^T, scatter-max =================
  if (w < 6) {
    const int wr4 = (w >= 3) ? 1 : 0;    // rows wr4*48..+47
    const int wc4 = w - wr4 * 3;         // cols wc4*32..+31
    facc bd[3][2];
    {
      facc z4 = {0.f, 0.f, 0.f, 0.f};
      #pragma unroll
      for (int i = 0; i < 3; ++i)
        #pragma unroll
        for (int j = 0; j < 2; ++j) bd[i][j] = z4;
    }
    #pragma unroll
    for (int kt = 0; kt < 8; ++kt) {
      bfrag a[3], bb[2];
      #pragma unroll
      for (int i = 0; i < 3; ++i)
        a[i] = *(const bfrag*)tptr(bufT, wr4 * 48 + i * 16 + lr, (kt << 5) + (lg << 3));
      #pragma unroll
      for (int j = 0; j < 2; ++j)
        bb[j] = *(const bfrag*)tptr(bufA, wc4 * 32 + j * 16 + lr, (kt << 5) + (lg << 3));
      #pragma unroll
      for (int i = 0; i < 3; ++i)
        #pragma unroll
        for (int j = 0; j < 2; ++j)
          bd[i][j] = __builtin_amdgcn_mfma_f32_16x16x32_bf16(a[i], bb[j], bd[i][j], 0, 0, 0);
    }
    // scatter straight from accumulators
    #pragma unroll
    for (int j = 0; j < 2; ++j) {
      const int colb = wc4 * 32 + j * 16 + lr;
      const float bet = (colb < 81) ? beta[colb] : 0.f;
      #pragma unroll
      for (int i = 0; i < 3; ++i)
        #pragma unroll
        for (int r = 0; r < 4; ++r) {
          const int rowb = wr4 * 48 + i * 16 + (lg << 2) + r;
          const float v = bd[i][j][r] * 0.0625f;
          if (rowb < 81 && colb < 81) {
            const float vv = v + alpha[rowb] + bet;
            const int2 iv = inv12[rowb * 81 + colb];
            const u32 ev = encf(vv);
            if (iv.x >= 0) atomicMax(&pol[iv.x], ev);
            if (iv.y >= 0) atomicMax(&pol[iv.y], ev);
          } else if (rowb >= 81 && rowb < 88 && colb < 81) {
            pol[1620 + (rowb - 81) * 81 + colb] = encf(v + dqc[rowb - 81] * 0.0625f);
          }
        }
    }
  }
  __syncthreads();

  // ================= phase 5: decode + store =================
  if (isbf) {
    u16* ob = (u16*)out + (size_t)b * 2187u;
    for (int p2 = tid; p2 < 2187; p2 += 512) ob[p2] = f2b(decf(pol[p2]));
  } else {
    float* ob = (float*)out + (size_t)b * 2187u;
    for (int p2 = tid; p2 < 2187; p2 += 512) ob[p2] = decf(pol[p2]);
  }
}

// ---------------- launcher ----------------
extern "C" void kernel_launch(void* const* d_in, const int* in_sizes, int n_in,
                              void* d_out, int out_size, void* d_ws, size_t ws_size,
                              hipStream_t stream) {
  const void* x        = d_in[0];
  const void* W_embed  = d_in[1];
  const void* b_embed  = d_in[2];
  const void* Wq       = d_in[3];
  const void* bq       = d_in[4];
  const void* Wk       = d_in[5];
  const void* bk_      = d_in[6];
  const void* dq       = d_in[7];
  const int* valid_idx         = (const int*)d_in[8];
  const int* policy_idx        = (const int*)d_in[9];
  const int* promo_idx         = (const int*)d_in[10];
  const int* promo_policy_idx  = (const int*)d_in[11];
  const int n_valid = in_sizes[8];
  const int n_promo = in_sizes[10];
  const int B = in_sizes[0] / 20736;   // 81*256

  // ws layout
  char* ws = (char*)d_ws;
  u16* Wt_lin    = (u16*)(ws);               // 131072
  u16* Wqkt_lin  = (u16*)(ws + 131072);      // 131072
  u16* Wt_tl     = (u16*)(ws + 262144);      // 131072
  u16* Wqkt_tl   = (u16*)(ws + 393216);      // 131072
  u16* uvwt      = (u16*)(ws + 524288);      // 8192
  u16* dqkp      = (u16*)(ws + 532480);      // 8192
  float* uvec    = (float*)(ws + 540672);    // 1024
  float* wvec    = (float*)(ws + 541696);    // 1024
  float* dqc     = (float*)(ws + 542720);    // 64
  int* dflag     = (int*)(ws + 542784);      // 64
  int2* inv12    = (int2*)(ws + 542848);     // 52488
  if (ws_size < 600000) return;

  detect_dtype_kernel<<<dim3(1), dim3(256), 0, stream>>>(x, dflag);
  prep_transpose_kernel<<<dim3(16), dim3(256), 0, stream>>>(W_embed, Wt_lin, dflag);
  prep_wqk_kernel<<<dim3(256), dim3(256), 0, stream>>>(Wq, Wk, Wqkt_lin, dflag);
  prep_vec_kernel<<<dim3(18), dim3(256), 0, stream>>>(Wq, Wk, bq, bk_, dq,
                                                      dqkp, uvec, wvec, dqc, dflag);
  prep_pack_tiled<<<dim3(32), dim3(256), 0, stream>>>(Wt_lin, Wt_tl);
  prep_pack_tiled<<<dim3(32), dim3(256), 0, stream>>>(Wqkt_lin, Wqkt_tl);
  prep_uvw_tiled<<<dim3(2), dim3(256), 0, stream>>>(uvec, wvec, uvwt);
  prep_inv_init_kernel<<<dim3(26), dim3(256), 0, stream>>>(inv12);
  int mx = n_valid > n_promo ? n_valid : n_promo;
  prep_inv_scatter_kernel<<<dim3((mx + 255) / 256), dim3(256), 0, stream>>>(
      valid_idx, policy_idx, promo_idx, promo_policy_idx, n_valid, n_promo, inv12);

  (void)hipFuncSetAttribute((const void*)dirpolicy_onepass,
                            hipFuncAttributeMaxDynamicSharedMemorySize, LDS_TOTAL);
  dirpolicy_onepass<<<dim3(B), dim3(512), LDS_TOTAL, stream>>>(
      x, b_embed, Wt_tl, Wqkt_tl, uvwt, dqkp, dqc, inv12, d_out, dflag);
}